// Round 5
// baseline (1461.817 us; speedup 1.0000x reference)
//
#include <hip/hip_runtime.h>

typedef _Float16 h2 __attribute__((ext_vector_type(2)));
typedef _Float16 h8 __attribute__((ext_vector_type(8)));
typedef float f4v __attribute__((ext_vector_type(4)));

#define U_DIM 256
#define M_DIM 256
#define T_DIM 512

#if defined(__has_builtin)
#if __has_builtin(__builtin_amdgcn_fdot2)
#define HAVE_FDOT2 1
#endif
#endif

__device__ __forceinline__ float fdot2f(h2 a, h2 b, float c) {
#ifdef HAVE_FDOT2
  return __builtin_amdgcn_fdot2(a, b, c, false);
#else
  return fmaf((float)a[0], (float)b[0], fmaf((float)a[1], (float)b[1], c));
#endif
}

__device__ __forceinline__ float fast_sigmoid(float z) {
  return __builtin_amdgcn_rcpf(1.f + __expf(-z));
}
__device__ __forceinline__ float fast_tanh(float z) {
  return fmaf(2.f, __builtin_amdgcn_rcpf(1.f + __expf(-2.f * z)), -1.f);
}

// DPP butterfly add over 8-lane groups: masks {1,2,7} basis of (Z2)^3.
template <int CTRL>
__device__ __forceinline__ float dpp_xadd(float x) {
  int y = __builtin_amdgcn_update_dpp(0, __float_as_int(x), CTRL, 0xF, 0xF, true);
  return x + __int_as_float(y);
}
__device__ __forceinline__ float reduce8(float x) {
  x = dpp_xadd<0xB1>(x);   // quad_perm [1,0,3,2] : xor 1
  x = dpp_xadd<0x4E>(x);   // quad_perm [2,3,0,1] : xor 2
  x = dpp_xadd<0x141>(x);  // row_half_mirror     : xor 7
  return x;
}

// ---------------- prep: x fp32 -> fp16 (same [M][T][256] layout) ------------
__global__ void conv_x(const float* __restrict__ x, h8* __restrict__ x16, int n8) {
  int i = blockIdx.x * 256 + threadIdx.x;
  if (i >= n8) return;
  const float4* p = (const float4*)(x + (size_t)i * 8);
  float4 v0 = p[0], v1 = p[1];
  h8 o = {(_Float16)v0.x, (_Float16)v0.y, (_Float16)v0.z, (_Float16)v0.w,
          (_Float16)v1.x, (_Float16)v1.y, (_Float16)v1.z, (_Float16)v1.w};
  x16[i] = o;
}

// ------- prep: x-projection weights -> fp16 TRANSPOSED [mtx][n][k] ----------
__global__ void prep_xw(const float* __restrict__ wux, const float* __restrict__ wrx,
                        const float* __restrict__ wcx, h8* __restrict__ wt16) {
  int idx = blockIdx.x * 256 + threadIdx.x;   // 0..24575
  int mtx = idx >> 13;
  int rem = idx & 8191;
  int n = rem >> 5;
  int kv = rem & 31;
  const float* W = (mtx == 0) ? wux : ((mtx == 1) ? wrx : wcx);
  h8 o;
#pragma unroll
  for (int e = 0; e < 8; ++e) o[e] = (_Float16)W[(size_t)(kv * 8 + e) * U_DIM + n];
  wt16[idx] = o;
}

// ---------------- prep: recurrent weights fp16, K32/R2 layout ---------------
// 1024-thread recurrence: thread tid = 8g+s owns outputs {2g, 2g+1} and
// k-slice [32s,32s+32).  w16[(mtx*1024+tid)*8 + (o*4+v)][e] = W[32s+8v+e][2g+o]
__global__ void prep_w(const float* __restrict__ wuc, const float* __restrict__ wrc,
                       const float* __restrict__ wcc, h8* __restrict__ w16) {
  int idx = blockIdx.x * 256 + threadIdx.x;   // 0..24575
  int mtx = idx >> 13;
  int rem = idx & 8191;
  int tid = rem >> 3;
  int q   = rem & 7;
  int o = q >> 2, v = q & 3;
  int g = tid >> 3, s = tid & 7;
  const float* W = (mtx == 0) ? wuc : ((mtx == 1) ? wrc : wcc);
  int col = 2 * g + o;
  int k0 = 32 * s + 8 * v;
  h8 out;
#pragma unroll
  for (int e = 0; e < 8; ++e) out[e] = (_Float16)W[(size_t)(k0 + e) * U_DIM + col];
  w16[idx] = out;
}

// ---------------- xproj via fp16 MFMA, fp16 OUTPUT (unchanged) --------------
__global__ __launch_bounds__(256, 2)
void xproj_mfma(const h8* __restrict__ x16, const h8* __restrict__ wt16,
                const float* __restrict__ Bu, const float* __restrict__ Br,
                const float* __restrict__ Bc,
                _Float16* __restrict__ XU, _Float16* __restrict__ XR,
                _Float16* __restrict__ XC, int t0, int len) {
  const int mtx = blockIdx.z;
  const float* Bv = (mtx == 0) ? Bu : ((mtx == 1) ? Br : Bc);
  _Float16* O = (mtx == 0) ? XU : ((mtx == 1) ? XR : XC);
  const h8* W = wt16 + (size_t)mtx * 256 * 32;

  __shared__ _Float16 a_sh[128][40];
  __shared__ _Float16 b_sh[128][40];

  const int tid = threadIdx.x;
  const int r0 = blockIdx.x * 128;
  const int c0 = blockIdx.y * 128;

  const int srow = tid >> 1;
  const int spart = tid & 1;
  const int r = r0 + srow;
  const int mm = r / len;
  const int tc = r - mm * len;
  const h8* arow = x16 + ((size_t)mm * T_DIM + (size_t)(t0 + tc)) * 32;
  const h8* brow = W + (size_t)(c0 + srow) * 32;

  const int lane = tid & 63;
  const int w = tid >> 6;
  const int quad = lane >> 4;
  const int mrow = lane & 15;

  f4v acc[2][8];
#pragma unroll
  for (int fr = 0; fr < 2; ++fr)
#pragma unroll
    for (int fc = 0; fc < 8; ++fc) acc[fr][fc] = f4v{0.f, 0.f, 0.f, 0.f};

  for (int k8 = 0; k8 < 32; k8 += 4) {
    h8 a0 = arow[k8 + 2 * spart];
    h8 a1 = arow[k8 + 2 * spart + 1];
    h8 b0 = brow[k8 + 2 * spart];
    h8 b1 = brow[k8 + 2 * spart + 1];
    __syncthreads();
    *(h8*)&a_sh[srow][spart * 16]     = a0;
    *(h8*)&a_sh[srow][spart * 16 + 8] = a1;
    *(h8*)&b_sh[srow][spart * 16]     = b0;
    *(h8*)&b_sh[srow][spart * 16 + 8] = b1;
    __syncthreads();
    h8 af0 = *(const h8*)&a_sh[32 * w + mrow][quad * 8];
    h8 af1 = *(const h8*)&a_sh[32 * w + 16 + mrow][quad * 8];
#pragma unroll
    for (int fc = 0; fc < 8; ++fc) {
      h8 bf = *(const h8*)&b_sh[fc * 16 + mrow][quad * 8];
      acc[0][fc] = __builtin_amdgcn_mfma_f32_16x16x32_f16(af0, bf, acc[0][fc], 0, 0, 0);
      acc[1][fc] = __builtin_amdgcn_mfma_f32_16x16x32_f16(af1, bf, acc[1][fc], 0, 0, 0);
    }
  }

#pragma unroll
  for (int fc = 0; fc < 8; ++fc) {
    int col = c0 + fc * 16 + mrow;
    float bb = Bv[col];
#pragma unroll
    for (int fr = 0; fr < 2; ++fr)
#pragma unroll
      for (int reg = 0; reg < 4; ++reg) {
        int rr = r0 + 32 * w + fr * 16 + quad * 4 + reg;
        O[(size_t)rr * U_DIM + col] = (_Float16)(acc[fr][fc][reg] + bb);
      }
  }
}

// ---------------- recurrence: 1024 thr, K32/R2, DPP reduce ------------------
// r3/r4 post-mortem: two attribute nulls.  Root cause is ARITHMETIC, not the
// allocator: VRF = 512 regs/SIMD; a 512-thr block needs 2 waves/SIMD -> hard
// 256-reg/wave cap; the old structure wants 192 weight regs + ~60-110 working
// = over cap -> compiler MUST park/reload weights (the ~330 excess VALU
// instr/thread/step).  Fix by design: 1024 threads, thread owns 2 ADJACENT
// outputs {2g,2g+1} x 32-k slice -> weights = 3*2*32*2B = 96 regs, working
// ~26 -> ~122 <= 128 (the budget __launch_bounds__(1024) enforces, 4 waves/
// SIMD).  Bonuses: one dword gate load covers both outputs; no post-reduce
// cndmask selects (pu0/pu1 ARE the thread's outputs); 4 waves/SIMD hides
// latency 2x better.  Diagnostic: VGPR_Count ~125-128, Occupancy ~47%.
__global__ __launch_bounds__(1024)
void gru_rec(const _Float16* __restrict__ XU, const _Float16* __restrict__ XR,
             const _Float16* __restrict__ XC, const h8* __restrict__ w16,
             const float* __restrict__ c_in, float* __restrict__ c_out, int len) {
  const int m = blockIdx.x;
  const int tid = threadIdx.x;
  const int g = tid >> 3;                     // 0..127 -> outputs 2g, 2g+1
  const int s = tid & 7;                      // k-slice [32s, 32s+32)
  const int cb = 5 * s;                       // padded h8 chunk base
  const int j0 = 2 * g;
  // halfword index of j0 in the padded LDS layout (chunk pad = 1 h8 per 4)
  const int hw = (5 * (j0 >> 5) + ((j0 & 31) >> 3)) * 8 + (j0 & 7);
  const bool wr = (s == 0);

  __shared__ h8 ch8[40];
  __shared__ h8 hh8[40];
  _Float16* cwp = (_Float16*)ch8;
  _Float16* hwp = (_Float16*)hh8;

  const h8* wub = w16 + (size_t)tid * 8;
  const h8* wrb = wub + 8192;
  const h8* wcb = wub + 16384;

#define DECL_W(l) h8 wu##l = wub[l]; h8 wr##l = wrb[l]; h8 wc##l = wcb[l];
  DECL_W(0)  DECL_W(1)  DECL_W(2)  DECL_W(3)
  DECL_W(4)  DECL_W(5)  DECL_W(6)  DECL_W(7)
#undef DECL_W

  float2 cc = *(const float2*)(c_in + m * U_DIM + j0);
  float cj0 = cc.x, cj1 = cc.y;
  if (wr) *(h2*)(cwp + hw) = h2{(_Float16)cj0, (_Float16)cj1};

  const char* pU = (const char*)(XU + (size_t)m * len * U_DIM) + 4 * g;
  const char* pR = (const char*)(XR + (size_t)m * len * U_DIM) + 4 * g;
  const char* pC = (const char*)(XC + (size_t)m * len * U_DIM) + 4 * g;

  int off = 0;
  h2 vu = *(const h2*)(pU + off);
  h2 vr = *(const h2*)(pR + off);
  h2 vc = *(const h2*)(pC + off);

  __syncthreads();

#define DOT8(acc, cv, w)                                                  \
  acc = fdot2f(h2{cv[0], cv[1]}, h2{w[0], w[1]}, acc);                    \
  acc = fdot2f(h2{cv[2], cv[3]}, h2{w[2], w[3]}, acc);                    \
  acc = fdot2f(h2{cv[4], cv[5]}, h2{w[4], w[5]}, acc);                    \
  acc = fdot2f(h2{cv[6], cv[7]}, h2{w[6], w[7]}, acc);

#define PASS1V(v, a, b) { h8 cv = ch8[cb + v];                            \
  DOT8(pu0, cv, wu##a) DOT8(pu1, cv, wu##b)                               \
  DOT8(pr0, cv, wr##a) DOT8(pr1, cv, wr##b) }

#define PASS2V(v, a, b) { h8 hv = hh8[cb + v];                            \
  DOT8(pc0, hv, wc##a) DOT8(pc1, hv, wc##b) }

  for (int t = 0; t < len; ++t) {
    int offn = off + ((t + 1 < len) ? (U_DIM * 2) : 0);
    h2 nu = *(const h2*)(pU + offn);
    h2 nr = *(const h2*)(pR + offn);
    h2 nc = *(const h2*)(pC + offn);

    float pu0 = 0.f, pu1 = 0.f, pr0 = 0.f, pr1 = 0.f;
    PASS1V(0, 0, 4)
    PASS1V(1, 1, 5)
    PASS1V(2, 2, 6)
    PASS1V(3, 3, 7)

    pu0 = reduce8(pu0); pu1 = reduce8(pu1);
    pr0 = reduce8(pr0); pr1 = reduce8(pr1);

    float gu0 = fast_sigmoid(pu0 + (float)vu[0]);
    float gu1 = fast_sigmoid(pu1 + (float)vu[1]);
    float gr0 = fast_sigmoid(pr0 + (float)vr[0]);
    float gr1 = fast_sigmoid(pr1 + (float)vr[1]);
    if (wr) *(h2*)(hwp + hw) = h2{(_Float16)(gr0 * cj0), (_Float16)(gr1 * cj1)};
    __syncthreads();

    float pc0 = 0.f, pc1 = 0.f;
    PASS2V(0, 0, 4)
    PASS2V(1, 1, 5)
    PASS2V(2, 2, 6)
    PASS2V(3, 3, 7)

    pc0 = reduce8(pc0); pc1 = reduce8(pc1);

    float cd0 = fast_tanh(pc0 + (float)vc[0]);
    float cd1 = fast_tanh(pc1 + (float)vc[1]);
    cj0 = fmaf(gu0, cd0 - cj0, cj0);
    cj1 = fmaf(gu1, cd1 - cj1, cj1);
    if (wr) *(h2*)(cwp + hw) = h2{(_Float16)cj0, (_Float16)cj1};

    vu = nu; vr = nr; vc = nc; off = offn;
    __syncthreads();
  }

#undef DOT8
#undef PASS1V
#undef PASS2V

  if (wr) *(float2*)(c_out + m * U_DIM + j0) = float2{cj0, cj1};
}

// ---------------- host ------------------------------------------------------
extern "C" void kernel_launch(void* const* d_in, const int* in_sizes, int n_in,
                              void* d_out, int out_size, void* d_ws, size_t ws_size,
                              hipStream_t stream) {
  const float* x   = (const float*)d_in[0];
  const float* a0  = (const float*)d_in[1];
  const float* wcx = (const float*)d_in[2];
  const float* wcc = (const float*)d_in[3];
  const float* bc  = (const float*)d_in[4];
  const float* wux = (const float*)d_in[5];
  const float* wuc = (const float*)d_in[6];
  const float* bu  = (const float*)d_in[7];
  const float* wrx = (const float*)d_in[8];
  const float* wrc = (const float*)d_in[9];
  const float* br  = (const float*)d_in[10];
  float* out = (float*)d_out;

  const size_t x16_bytes = (size_t)M_DIM * T_DIM * U_DIM * 2;  // 67.1 MB
  const size_t wt_bytes  = 3ull * 256 * 32 * 16;               // 384 KB
  const size_t w16_bytes = 3ull * 1024 * 8 * 16;               // 384 KB
  const size_t fixed = x16_bytes + wt_bytes + w16_bytes;

  h8* x16  = (h8*)d_ws;
  h8* wt16 = (h8*)((char*)d_ws + x16_bytes);
  h8* w16  = (h8*)((char*)d_ws + x16_bytes + wt_bytes);
  _Float16* XU0 = (_Float16*)((char*)d_ws + fixed);

  size_t avail = (ws_size > fixed) ? (ws_size - fixed) : 0;
  const size_t perT = 3ull * M_DIM * U_DIM * 2;                // 393 KB / step
  int Tc = (int)(avail / perT);
  if (Tc > T_DIM) Tc = T_DIM;
  if (Tc < 1) Tc = 1;
  int nch = (T_DIM + Tc - 1) / Tc;
  Tc = (T_DIM + nch - 1) / nch;

  _Float16* XU = XU0;
  _Float16* XR = XU + (size_t)M_DIM * Tc * U_DIM;
  _Float16* XC = XR + (size_t)M_DIM * Tc * U_DIM;

  conv_x<<<16384, 256, 0, stream>>>(x, x16, M_DIM * T_DIM * U_DIM / 8);
  prep_xw<<<96, 256, 0, stream>>>(wux, wrx, wcx, wt16);
  prep_w<<<96, 256, 0, stream>>>(wuc, wrc, wcc, w16);

  for (int t0 = 0; t0 < T_DIM; t0 += Tc) {
    int lenc = (T_DIM - t0) < Tc ? (T_DIM - t0) : Tc;
    dim3 g((M_DIM * lenc) / 128, 2, 3);
    xproj_mfma<<<g, 256, 0, stream>>>(x16, wt16, bu, br, bc,
                                      XU, XR, XC, t0, lenc);
    gru_rec<<<M_DIM, 1024, 0, stream>>>(XU, XR, XC, w16,
                                        (t0 == 0 ? a0 : out), out, lenc);
  }
}

// Round 6
// 864.997 us; speedup vs baseline: 1.6900x; 1.6900x over previous
//
#include <hip/hip_runtime.h>

typedef _Float16 h8 __attribute__((ext_vector_type(8)));
typedef float f4v __attribute__((ext_vector_type(4)));

#define U_DIM 256
#define M_DIM 256
#define T_DIM 512

__device__ __forceinline__ float fast_sigmoid(float z) {
  return __builtin_amdgcn_rcpf(1.f + __expf(-z));
}
__device__ __forceinline__ float fast_tanh(float z) {
  return fmaf(2.f, __builtin_amdgcn_rcpf(1.f + __expf(-2.f * z)), -1.f);
}

// ---------------- prep: x fp32 -> fp16 (same [M][T][256] layout) ------------
__global__ void conv_x(const float* __restrict__ x, h8* __restrict__ x16, int n8) {
  int i = blockIdx.x * 256 + threadIdx.x;
  if (i >= n8) return;
  const float4* p = (const float4*)(x + (size_t)i * 8);
  float4 v0 = p[0], v1 = p[1];
  h8 o = {(_Float16)v0.x, (_Float16)v0.y, (_Float16)v0.z, (_Float16)v0.w,
          (_Float16)v1.x, (_Float16)v1.y, (_Float16)v1.z, (_Float16)v1.w};
  x16[i] = o;
}

// ------- prep: x-projection weights -> fp16 TRANSPOSED [mtx][n][k] ----------
__global__ void prep_xw(const float* __restrict__ wux, const float* __restrict__ wrx,
                        const float* __restrict__ wcx, h8* __restrict__ wt16) {
  int idx = blockIdx.x * 256 + threadIdx.x;   // 0..24575
  int mtx = idx >> 13;
  int rem = idx & 8191;
  int n = rem >> 5;
  int kv = rem & 31;
  const float* W = (mtx == 0) ? wux : ((mtx == 1) ? wrx : wcx);
  h8 o;
#pragma unroll
  for (int e = 0; e < 8; ++e) o[e] = (_Float16)W[(size_t)(kv * 8 + e) * U_DIM + n];
  wt16[idx] = o;
}

// --------- prep: recurrent weights fp16, MFMA B-fragment layout -------------
// (verbatim r2 layout -- r2 PASSED numerically, so this mapping is verified)
// w16[((mtx*16 + nt)*8 + kblk)*64 + lane][e] = W[kblk*32 + (lane>>4)*8 + e][nt*16 + (lane&15)]
__global__ void prep_w(const float* __restrict__ wuc, const float* __restrict__ wrc,
                       const float* __restrict__ wcc, h8* __restrict__ w16) {
  int idx = blockIdx.x * 256 + threadIdx.x;   // 0..24575
  int mtx = idx >> 13;
  int rem = idx & 8191;
  int nt = rem >> 9;
  int kblk = (rem >> 6) & 7;
  int ln = rem & 63;
  const float* W = (mtx == 0) ? wuc : ((mtx == 1) ? wrc : wcc);
  int col = nt * 16 + (ln & 15);
  int k0 = kblk * 32 + ((ln >> 4) << 3);
  h8 o;
#pragma unroll
  for (int e = 0; e < 8; ++e) o[e] = (_Float16)W[(size_t)(k0 + e) * U_DIM + col];
  w16[idx] = o;
}

// ------- xproj via fp16 MFMA; OUTPUT layout now X[t][m][col] fp16 -----------
// Layout change so gru_rec's per-lane gate loads are step-invariant + coalesced.
// len is a power of two (host enforces); lenlog = log2(len).
__global__ __launch_bounds__(256, 2)
void xproj_mfma(const h8* __restrict__ x16, const h8* __restrict__ wt16,
                const float* __restrict__ Bu, const float* __restrict__ Br,
                const float* __restrict__ Bc,
                _Float16* __restrict__ XU, _Float16* __restrict__ XR,
                _Float16* __restrict__ XC, int t0, int len, int lenlog) {
  const int mtx = blockIdx.z;
  const float* Bv = (mtx == 0) ? Bu : ((mtx == 1) ? Br : Bc);
  _Float16* O = (mtx == 0) ? XU : ((mtx == 1) ? XR : XC);
  const h8* W = wt16 + (size_t)mtx * 256 * 32;

  __shared__ _Float16 a_sh[128][40];
  __shared__ _Float16 b_sh[128][40];

  const int tid = threadIdx.x;
  const int r0 = blockIdx.x * 128;
  const int c0 = blockIdx.y * 128;

  const int srow = tid >> 1;
  const int spart = tid & 1;
  const int r = r0 + srow;
  const int mm = r >> lenlog;
  const int tc = r & (len - 1);
  const h8* arow = x16 + ((size_t)mm * T_DIM + (size_t)(t0 + tc)) * 32;
  const h8* brow = W + (size_t)(c0 + srow) * 32;

  const int lane = tid & 63;
  const int w = tid >> 6;
  const int quad = lane >> 4;
  const int mrow = lane & 15;

  f4v acc[2][8];
#pragma unroll
  for (int fr = 0; fr < 2; ++fr)
#pragma unroll
    for (int fc = 0; fc < 8; ++fc) acc[fr][fc] = f4v{0.f, 0.f, 0.f, 0.f};

  for (int k8 = 0; k8 < 32; k8 += 4) {
    h8 a0 = arow[k8 + 2 * spart];
    h8 a1 = arow[k8 + 2 * spart + 1];
    h8 b0 = brow[k8 + 2 * spart];
    h8 b1 = brow[k8 + 2 * spart + 1];
    __syncthreads();
    *(h8*)&a_sh[srow][spart * 16]     = a0;
    *(h8*)&a_sh[srow][spart * 16 + 8] = a1;
    *(h8*)&b_sh[srow][spart * 16]     = b0;
    *(h8*)&b_sh[srow][spart * 16 + 8] = b1;
    __syncthreads();
    h8 af0 = *(const h8*)&a_sh[32 * w + mrow][quad * 8];
    h8 af1 = *(const h8*)&a_sh[32 * w + 16 + mrow][quad * 8];
#pragma unroll
    for (int fc = 0; fc < 8; ++fc) {
      h8 bf = *(const h8*)&b_sh[fc * 16 + mrow][quad * 8];
      acc[0][fc] = __builtin_amdgcn_mfma_f32_16x16x32_f16(af0, bf, acc[0][fc], 0, 0, 0);
      acc[1][fc] = __builtin_amdgcn_mfma_f32_16x16x32_f16(af1, bf, acc[1][fc], 0, 0, 0);
    }
  }

#pragma unroll
  for (int fc = 0; fc < 8; ++fc) {
    int col = c0 + fc * 16 + mrow;
    float bb = Bv[col];
#pragma unroll
    for (int fr = 0; fr < 2; ++fr)
#pragma unroll
      for (int reg = 0; reg < 4; ++reg) {
        int rr = r0 + 32 * w + fr * 16 + quad * 4 + reg;
        int mI = rr >> lenlog;
        int tcI = rr & (len - 1);
        O[((size_t)tcI * 256 + mI) * 256 + col] = (_Float16)(acc[fr][fc][reg] + bb);
      }
  }
}

// ---------------- recurrence: MFMA, 1 m-row per block, 256 blocks -----------
// r5 post-mortem: 1024-thr forced a 64-reg budget -> scratch spill (WRITE_SIZE
// 6400KB), 1236us.  Conclusion across r1-r5: >=96 loop-invariant VALU operands
// always get parked (AGPR shuttle or scratch).  Escape: make MFMA the weight
// consumer -- MFMA reads AGPRs natively, so parked weights cost ZERO.
// r2 proved the fragment layouts but died on grid=16 (16 CUs streamed the
// gate bytes at scalar-load latency -> 31GB/s fetch-bound).  This version:
//   * 256 blocks (full machine), ONE m-row per block; MFMA rows 1..15 ride on
//     zeroed LDS rows (wasted matrix FLOPs are free -- MfmaUtil was 0.6%).
//   * all 3 weight mats as B-frags in regs/AGPR (48 h8 = 192 regs); working
//     set ~60 VGPR -> ~252 <= 256 @ 2 waves/SIMD (r2 compiled this split
//     clean: WRITE_SIZE 256KB, no spill -- that's the tripwire to re-check).
//   * gates from X[t][m][col]: 6 coalesced u16 loads/lane/step at
//     step-invariant offsets, double-buffered one step ahead (r1 pattern).
// Per wave/step: 16 ds_read_b128 + 48 mfma_16x16x32_f16 + ~60 VALU.
__global__ __launch_bounds__(512)
void gru_rec(const _Float16* __restrict__ XU, const _Float16* __restrict__ XR,
             const _Float16* __restrict__ XC, const h8* __restrict__ w16,
             const float* __restrict__ c_in, float* __restrict__ c_out, int len) {
  const int m = blockIdx.x;
  const int tid = threadIdx.x;
  const int lane = tid & 63;
  const int wv = tid >> 6;            // wave 0..7 owns cols [32wv, 32wv+32)
  const int rowq = lane >> 4;
  const int nlo = lane & 15;
  const int n0 = 32 * wv;
  const int col0 = n0 + nlo, col1 = n0 + 16 + nlo;

  __shared__ _Float16 c_sh[16][264];
  __shared__ _Float16 h_sh[16][264];

  // zero both tiles once; rows 1..15 stay zero forever (garbage-free MFMA A)
  for (int i = tid; i < 528; i += 512) {
    ((int4*)c_sh)[i] = int4{0, 0, 0, 0};
    ((int4*)h_sh)[i] = int4{0, 0, 0, 0};
  }

  // B-fragment weights, register/AGPR-resident for the whole scan
  const h8* wub = w16 + (size_t)wv * 1024 + lane;
  const h8* wrb = wub + 8192;
  const h8* wcb = wub + 16384;
  h8 wu[2][8], wr[2][8], wc[2][8];
#pragma unroll
  for (int i = 0; i < 2; ++i)
#pragma unroll
    for (int k = 0; k < 8; ++k) {
      wu[i][k] = wub[(i * 8 + k) * 64];
      wr[i][k] = wrb[(i * 8 + k) * 64];
      wc[i][k] = wcb[(i * 8 + k) * 64];
    }

  float c0 = 0.f, c1 = 0.f;
  if (rowq == 0) {
    c0 = c_in[m * U_DIM + col0];
    c1 = c_in[m * U_DIM + col1];
    c_sh[0][col0] = (_Float16)c0;
    c_sh[0][col1] = (_Float16)c1;
  }

  // gate pointers: X[t][m][col] -> step stride = 256*256 elems
  const _Float16* pU = XU + (size_t)m * U_DIM;
  const _Float16* pR = XR + (size_t)m * U_DIM;
  const _Float16* pC = XC + (size_t)m * U_DIM;
  const size_t TSTRIDE = (size_t)U_DIM * M_DIM;

  float xu0 = (float)pU[col0], xu1 = (float)pU[col1];
  float xr0 = (float)pR[col0], xr1 = (float)pR[col1];
  float xc0 = (float)pC[col0], xc1 = (float)pC[col1];

  __syncthreads();

  for (int t = 0; t < len; ++t) {
    const size_t bump = (t + 1 < len) ? TSTRIDE : 0;
    const _Float16* qU = pU + bump;
    const _Float16* qR = pR + bump;
    const _Float16* qC = pC + bump;
    float nu0 = (float)qU[col0], nu1 = (float)qU[col1];
    float nr0 = (float)qR[col0], nr1 = (float)qR[col1];
    float nc0 = (float)qC[col0], nc1 = (float)qC[col1];

    // ---- pass1: U = c@Wu, R = c@Wr ----
    f4v aU0 = f4v{0.f, 0.f, 0.f, 0.f}, aU1 = f4v{0.f, 0.f, 0.f, 0.f};
    f4v aR0 = f4v{0.f, 0.f, 0.f, 0.f}, aR1 = f4v{0.f, 0.f, 0.f, 0.f};
    const _Float16* cA = &c_sh[nlo][rowq * 8];
#pragma unroll
    for (int k = 0; k < 8; ++k) {
      h8 A = *(const h8*)(cA + k * 32);
      aU0 = __builtin_amdgcn_mfma_f32_16x16x32_f16(A, wu[0][k], aU0, 0, 0, 0);
      aU1 = __builtin_amdgcn_mfma_f32_16x16x32_f16(A, wu[1][k], aU1, 0, 0, 0);
      aR0 = __builtin_amdgcn_mfma_f32_16x16x32_f16(A, wr[0][k], aR0, 0, 0, 0);
      aR1 = __builtin_amdgcn_mfma_f32_16x16x32_f16(A, wr[1][k], aR1, 0, 0, 0);
    }

    float gu0 = 0.f, gu1 = 0.f;
    if (rowq == 0) {
      gu0 = fast_sigmoid(aU0[0] + xu0);
      gu1 = fast_sigmoid(aU1[0] + xu1);
      float gr0 = fast_sigmoid(aR0[0] + xr0);
      float gr1 = fast_sigmoid(aR1[0] + xr1);
      h_sh[0][col0] = (_Float16)(gr0 * c0);
      h_sh[0][col1] = (_Float16)(gr1 * c1);
    }
    __syncthreads();

    // ---- pass2: cand = h@Wc ----
    f4v aC0 = f4v{0.f, 0.f, 0.f, 0.f}, aC1 = f4v{0.f, 0.f, 0.f, 0.f};
    const _Float16* hA = &h_sh[nlo][rowq * 8];
#pragma unroll
    for (int k = 0; k < 8; ++k) {
      h8 A = *(const h8*)(hA + k * 32);
      aC0 = __builtin_amdgcn_mfma_f32_16x16x32_f16(A, wc[0][k], aC0, 0, 0, 0);
      aC1 = __builtin_amdgcn_mfma_f32_16x16x32_f16(A, wc[1][k], aC1, 0, 0, 0);
    }

    if (rowq == 0) {
      float cd0 = fast_tanh(aC0[0] + xc0);
      float cd1 = fast_tanh(aC1[0] + xc1);
      c0 = fmaf(gu0, cd0 - c0, c0);
      c1 = fmaf(gu1, cd1 - c1, c1);
      c_sh[0][col0] = (_Float16)c0;
      c_sh[0][col1] = (_Float16)c1;
    }

    xu0 = nu0; xu1 = nu1; xr0 = nr0; xr1 = nr1; xc0 = nc0; xc1 = nc1;
    pU = qU; pR = qR; pC = qC;
    __syncthreads();
  }

  if (rowq == 0) {
    c_out[m * U_DIM + col0] = c0;
    c_out[m * U_DIM + col1] = c1;
  }
}

// ---------------- host ------------------------------------------------------
extern "C" void kernel_launch(void* const* d_in, const int* in_sizes, int n_in,
                              void* d_out, int out_size, void* d_ws, size_t ws_size,
                              hipStream_t stream) {
  const float* x   = (const float*)d_in[0];
  const float* a0  = (const float*)d_in[1];
  const float* wcx = (const float*)d_in[2];
  const float* wcc = (const float*)d_in[3];
  const float* bc  = (const float*)d_in[4];
  const float* wux = (const float*)d_in[5];
  const float* wuc = (const float*)d_in[6];
  const float* bu  = (const float*)d_in[7];
  const float* wrx = (const float*)d_in[8];
  const float* wrc = (const float*)d_in[9];
  const float* br  = (const float*)d_in[10];
  float* out = (float*)d_out;

  const size_t x16_bytes = (size_t)M_DIM * T_DIM * U_DIM * 2;  // 67.1 MB
  const size_t wt_bytes  = 3ull * 256 * 32 * 16;               // 384 KB
  const size_t w16_bytes = 3ull * 16 * 8 * 64 * 16;            // 384 KB
  const size_t fixed = x16_bytes + wt_bytes + w16_bytes;

  h8* x16  = (h8*)d_ws;
  h8* wt16 = (h8*)((char*)d_ws + x16_bytes);
  h8* w16  = (h8*)((char*)d_ws + x16_bytes + wt_bytes);
  _Float16* XU0 = (_Float16*)((char*)d_ws + fixed);

  size_t avail = (ws_size > fixed) ? (ws_size - fixed) : 0;
  const size_t perT = 3ull * M_DIM * U_DIM * 2;                // 393 KB / step
  int Tc = (int)(avail / perT);
  if (Tc > T_DIM) Tc = T_DIM;
  if (Tc < 1) Tc = 1;
  // force power-of-two chunk (xproj/gru use shift/mask indexing)
  while (Tc & (Tc - 1)) Tc &= Tc - 1;
  int lenlog = __builtin_ctz((unsigned)Tc);

  _Float16* XU = XU0;
  _Float16* XR = XU + (size_t)M_DIM * Tc * U_DIM;
  _Float16* XC = XR + (size_t)M_DIM * Tc * U_DIM;

  conv_x<<<16384, 256, 0, stream>>>(x, x16, M_DIM * T_DIM * U_DIM / 8);
  prep_xw<<<96, 256, 0, stream>>>(wux, wrx, wcx, wt16);
  prep_w<<<96, 256, 0, stream>>>(wuc, wrc, wcc, w16);

  for (int t0 = 0; t0 < T_DIM; t0 += Tc) {
    int lenc = (T_DIM - t0) < Tc ? (T_DIM - t0) : Tc;  // == Tc (Tc | 512)
    dim3 g((M_DIM * lenc) / 128, 2, 3);
    xproj_mfma<<<g, 256, 0, stream>>>(x16, wt16, bu, br, bc,
                                      XU, XR, XC, t0, lenc, lenlog);
    gru_rec<<<M_DIM, 512, 0, stream>>>(XU, XR, XC, w16,
                                       (t0 == 0 ? a0 : out), out, lenc);
  }
}